// Round 10
// baseline (541.827 us; speedup 1.0000x reference)
//
#include <hip/hip_runtime.h>
#include <hip/hip_cooperative_groups.h>

#define BB 8
#define NN 4096
#define LL 4096
#define CC 256

typedef short bf16x8 __attribute__((ext_vector_type(8)));
typedef _Float16 f16x8 __attribute__((ext_vector_type(8)));
typedef __fp16 hf16x2 __attribute__((ext_vector_type(2)));  // cvt_pkrtz return type
typedef float f32x4 __attribute__((ext_vector_type(4)));

__device__ __forceinline__ short f2bf(float f) {
  union { float f; unsigned u; } v; v.f = f;
  unsigned r = v.u + 0x7fffu + ((v.u >> 16) & 1u);
  return (short)(r >> 16);
}
__device__ __forceinline__ bf16x8 ld8(const float* __restrict__ fp) {
  float4 a = *(const float4*)fp;
  float4 b = *(const float4*)(fp + 4);
  bf16x8 r;
  r[0] = f2bf(a.x); r[1] = f2bf(a.y); r[2] = f2bf(a.z); r[3] = f2bf(a.w);
  r[4] = f2bf(b.x); r[5] = f2bf(b.y); r[6] = f2bf(b.z); r[7] = f2bf(b.w);
  return r;
}

// ---------------------------------------------------------------------------
// Phase 0: projections.  blocks 0..511: Kt (scaled bf16 [b][l][32]) + Vt2
// (RAW f16 [b][32][l] -- normalization folded into P in phase 3) + zero Zb.
// blocks 512..1023: Qb (bf16 [b][n][32]).
// ---------------------------------------------------------------------------
__device__ __forceinline__ void phase0(
    int bid, int tid, int w, int lo, int q,
    const float* __restrict__ graph, const float* __restrict__ img,
    const float* __restrict__ Wq, const float* __restrict__ bq,
    const float* __restrict__ Wk, const float* __restrict__ bk,
    const float* __restrict__ Wv, const float* __restrict__ bv,
    short* __restrict__ Qb, short* __restrict__ Kt,
    _Float16* __restrict__ Vt2, float* __restrict__ Zb)
{
  if (bid < 512) {
    const int b = bid >> 6;
    if (tid < 64) Zb[(size_t)b * LL + ((bid & 63) << 6) + tid] = 0.0f;
    const int lt = ((bid & 63) << 6) + (w << 4);
    f32x4 aK0 = {0,0,0,0}, aK1 = {0,0,0,0}, aV0 = {0,0,0,0}, aV1 = {0,0,0,0};
    const float* ib = img + (size_t)b * CC * LL + lt + lo;
    #pragma unroll
    for (int cs = 0; cs < 8; ++cs) {
      const int c0 = cs * 32 + q * 8;
      bf16x8 bi;
      #pragma unroll
      for (int j = 0; j < 8; ++j) bi[j] = f2bf(ib[(size_t)(c0 + j) * LL]);
      bf16x8 wk0 = ld8(Wk + lo * CC + c0);
      bf16x8 wk1 = ld8(Wk + (lo + 16) * CC + c0);
      bf16x8 wv0 = ld8(Wv + lo * CC + c0);
      bf16x8 wv1 = ld8(Wv + (lo + 16) * CC + c0);
      aK0 = __builtin_amdgcn_mfma_f32_16x16x32_bf16(wk0, bi, aK0, 0, 0, 0);
      aK1 = __builtin_amdgcn_mfma_f32_16x16x32_bf16(wk1, bi, aK1, 0, 0, 0);
      aV0 = __builtin_amdgcn_mfma_f32_16x16x32_bf16(wv0, bi, aV0, 0, 0, 0);
      aV1 = __builtin_amdgcn_mfma_f32_16x16x32_bf16(wv1, bi, aV1, 0, 0, 0);
    }
    const float kscale = 0.2550348663f;  // log2(e)/sqrt(32)
    const size_t row = ((size_t)b * LL + lt + lo) * 32;
    short4 s0, s1;
    s0.x = f2bf((aK0[0] + bk[q * 4 + 0]) * kscale);
    s0.y = f2bf((aK0[1] + bk[q * 4 + 1]) * kscale);
    s0.z = f2bf((aK0[2] + bk[q * 4 + 2]) * kscale);
    s0.w = f2bf((aK0[3] + bk[q * 4 + 3]) * kscale);
    s1.x = f2bf((aK1[0] + bk[16 + q * 4 + 0]) * kscale);
    s1.y = f2bf((aK1[1] + bk[16 + q * 4 + 1]) * kscale);
    s1.z = f2bf((aK1[2] + bk[16 + q * 4 + 2]) * kscale);
    s1.w = f2bf((aK1[3] + bk[16 + q * 4 + 3]) * kscale);
    *(short4*)(Kt + row + q * 4) = s0;
    *(short4*)(Kt + row + 16 + q * 4) = s1;
    // V raw -> [b][32 o][l] (same cvt_pkrtz rounding as before)
    union { hf16x2 h[2]; __fp16 e[4]; } p0, p1;
    p0.h[0] = __builtin_amdgcn_cvt_pkrtz(aV0[0] + bv[q * 4 + 0], aV0[1] + bv[q * 4 + 1]);
    p0.h[1] = __builtin_amdgcn_cvt_pkrtz(aV0[2] + bv[q * 4 + 2], aV0[3] + bv[q * 4 + 3]);
    p1.h[0] = __builtin_amdgcn_cvt_pkrtz(aV1[0] + bv[16 + q * 4 + 0], aV1[1] + bv[16 + q * 4 + 1]);
    p1.h[1] = __builtin_amdgcn_cvt_pkrtz(aV1[2] + bv[16 + q * 4 + 2], aV1[3] + bv[16 + q * 4 + 3]);
    const size_t vbase = (size_t)b * 32 * LL + lt + lo;
    #pragma unroll
    for (int r = 0; r < 4; ++r) {
      Vt2[vbase + (size_t)(q * 4 + r) * LL] = p0.e[r];
      Vt2[vbase + (size_t)(16 + q * 4 + r) * LL] = p1.e[r];
    }
  } else {
    const int t = bid - 512;
    const int b = t >> 6;
    const int nt = ((t & 63) << 6) + (w << 4);
    bf16x8 ag = ld8(graph + ((size_t)b * NN + nt + lo) * 32 + q * 8);
    bf16x8 w0 = ld8(Wq + lo * 32 + q * 8);
    bf16x8 w1 = ld8(Wq + (lo + 16) * 32 + q * 8);
    f32x4 z = {0,0,0,0};
    f32x4 a0 = __builtin_amdgcn_mfma_f32_16x16x32_bf16(ag, w0, z, 0, 0, 0);
    f32x4 a1 = __builtin_amdgcn_mfma_f32_16x16x32_bf16(ag, w1, z, 0, 0, 0);
    const float b0 = bq[lo], b1 = bq[lo + 16];
    #pragma unroll
    for (int r = 0; r < 4; ++r) {
      const size_t rowq = ((size_t)b * NN + nt + q * 4 + r) * 32;
      Qb[rowq + lo] = f2bf(a0[r] + b0);
      Qb[rowq + 16 + lo] = f2bf(a1[r] + b1);
    }
  }
}

// ---------------------------------------------------------------------------
// Phase 1: partial softmax denominators on the 1024-block grid.
// Block (b = bid&7 XCD-pinned, t = bid>>3): l-tile lt = t>>1 (64 l), n-half
// t&1; wave w covers 512 n in 32 iterations.  8 waves per (b,l-tile) total.
// ---------------------------------------------------------------------------
__device__ __forceinline__ void phase1(
    int bid, int w, int lo, int q,
    const short* __restrict__ Qb, const short* __restrict__ Kt,
    float* __restrict__ Zb)
{
  const int b = bid & 7;
  const int t = bid >> 3;
  const int l0 = (t >> 1) << 6;
  const int nbase = (t & 1) * 2048 + w * 512;
  bf16x8 kf[4];
  #pragma unroll
  for (int f = 0; f < 4; ++f)
    kf[f] = *(const bf16x8*)(Kt + ((size_t)b * LL + l0 + f * 16 + lo) * 32 + q * 8);
  float za[4][4] = {{0}};
  const short* qbase = Qb + ((size_t)b * NN + nbase + lo) * 32 + q * 8;
  #pragma unroll 4
  for (int it = 0; it < 32; ++it) {
    bf16x8 qf = *(const bf16x8*)(qbase + it * 512);
    #pragma unroll
    for (int f = 0; f < 4; ++f) {
      f32x4 z = {0,0,0,0};
      f32x4 c = __builtin_amdgcn_mfma_f32_16x16x32_bf16(kf[f], qf, z, 0, 0, 0);
      #pragma unroll
      for (int r = 0; r < 4; ++r) za[f][r] += __builtin_amdgcn_exp2f(c[r]);
    }
  }
  #pragma unroll
  for (int m = 1; m < 16; m <<= 1)
    #pragma unroll
    for (int f = 0; f < 4; ++f)
      #pragma unroll
      for (int r = 0; r < 4; ++r)
        za[f][r] += __shfl_xor(za[f][r], m, 64);
  if (lo == 0) {
    #pragma unroll
    for (int f = 0; f < 4; ++f)
      #pragma unroll
      for (int r = 0; r < 4; ++r)
        atomicAdd(&Zb[(size_t)b * LL + l0 + f * 16 + q * 4 + r], za[f][r]);
  }
}

// ---------------------------------------------------------------------------
// Phase 2: Zi = 4096 / Z  (32768 entries, 32 per block).
// ---------------------------------------------------------------------------
__device__ __forceinline__ void phase2(
    int bid, int tid, const float* __restrict__ Zb, float* __restrict__ Zi)
{
  if (tid < 32) {
    const int i = bid * 32 + tid;
    Zi[i] = 4096.0f * __builtin_amdgcn_rcpf(Zb[i]);
  }
}

// ---------------------------------------------------------------------------
// Phase 3: r7's proven kc structure (lag-1 pipeline, per-wave P ping-pong,
// V in regs, XCD-pinned b=bid&7), with P scaled by Zi[l] after exp2 (folds
// the old kb2 normalization into P; V consumed raw).  Zi float4 loaded at
// body top (broadcast within 16-lane groups, L2-hot).
// ---------------------------------------------------------------------------
#define KC_BODY(LC, PWR, PRD, DOPV)                                           \
  {                                                                           \
    const int lbase_ = (LC) * 64;                                             \
    const int lcn_ = ((LC) + 1 < lc0 + 16) ? (LC) + 1 : (LC);                 \
    float4 zi_[4];                                                            \
    _Pragma("unroll")                                                         \
    for (int f = 0; f < 4; ++f)                                               \
      zi_[f] = *(const float4*)(zib + lbase_ + f * 16);                       \
    bf16x8 kfN_[4];                                                           \
    _Pragma("unroll")                                                         \
    for (int f = 0; f < 4; ++f)                                               \
      kfN_[f] = *(const bf16x8*)(ktb + (size_t)(lcn_ * 64 + f * 16) * 32);    \
    f16x8 vN0_ = *(const f16x8*)(vb0 + lbase_ + q * 8);                       \
    f16x8 vN1_ = *(const f16x8*)(vb0 + lbase_ + 32 + q * 8);                  \
    f16x8 vN2_ = *(const f16x8*)(vb1 + lbase_ + q * 8);                       \
    f16x8 vN3_ = *(const f16x8*)(vb1 + lbase_ + 32 + q * 8);                  \
    _Pragma("unroll")                                                         \
    for (int f = 0; f < 4; ++f) {                                             \
      f32x4 z_ = {0, 0, 0, 0};                                                \
      f32x4 c0_ = __builtin_amdgcn_mfma_f32_16x16x32_bf16(kfC[f], qf0, z_, 0, 0, 0); \
      f32x4 c1_ = __builtin_amdgcn_mfma_f32_16x16x32_bf16(kfC[f], qf1, z_, 0, 0, 0); \
      union { hf16x2 h[2]; uint2 u; } pk0_, pk1_;                             \
      pk0_.h[0] = __builtin_amdgcn_cvt_pkrtz(                                 \
          __builtin_amdgcn_exp2f(c0_[0]) * zi_[f].x,                          \
          __builtin_amdgcn_exp2f(c0_[1]) * zi_[f].y);                         \
      pk0_.h[1] = __builtin_amdgcn_cvt_pkrtz(                                 \
          __builtin_amdgcn_exp2f(c0_[2]) * zi_[f].z,                          \
          __builtin_amdgcn_exp2f(c0_[3]) * zi_[f].w);                         \
      pk1_.h[0] = __builtin_amdgcn_cvt_pkrtz(                                 \
          __builtin_amdgcn_exp2f(c1_[0]) * zi_[f].x,                          \
          __builtin_amdgcn_exp2f(c1_[1]) * zi_[f].y);                         \
      pk1_.h[1] = __builtin_amdgcn_cvt_pkrtz(                                 \
          __builtin_amdgcn_exp2f(c1_[2]) * zi_[f].z,                          \
          __builtin_amdgcn_exp2f(c1_[3]) * zi_[f].w);                         \
      *(uint2*)&(PWR)[lo * 72 + f * 16 + q * 4] = pk0_.u;                     \
      *(uint2*)&(PWR)[(16 + lo) * 72 + f * 16 + q * 4] = pk1_.u;              \
    }                                                                         \
    if (DOPV) {                                                               \
      f16x8 pa00_ = *(const f16x8*)&(PRD)[lo * 72 + q * 8];                   \
      f16x8 pa01_ = *(const f16x8*)&(PRD)[lo * 72 + 32 + q * 8];              \
      f16x8 pa10_ = *(const f16x8*)&(PRD)[(16 + lo) * 72 + q * 8];            \
      f16x8 pa11_ = *(const f16x8*)&(PRD)[(16 + lo) * 72 + 32 + q * 8];       \
      m00 = __builtin_amdgcn_mfma_f32_16x16x32_f16(pa00_, vC0, m00, 0, 0, 0); \
      m10 = __builtin_amdgcn_mfma_f32_16x16x32_f16(pa10_, vC0, m10, 0, 0, 0); \
      m01 = __builtin_amdgcn_mfma_f32_16x16x32_f16(pa00_, vC2, m01, 0, 0, 0); \
      m11 = __builtin_amdgcn_mfma_f32_16x16x32_f16(pa10_, vC2, m11, 0, 0, 0); \
      m00 = __builtin_amdgcn_mfma_f32_16x16x32_f16(pa01_, vC1, m00, 0, 0, 0); \
      m10 = __builtin_amdgcn_mfma_f32_16x16x32_f16(pa11_, vC1, m10, 0, 0, 0); \
      m01 = __builtin_amdgcn_mfma_f32_16x16x32_f16(pa01_, vC3, m01, 0, 0, 0); \
      m11 = __builtin_amdgcn_mfma_f32_16x16x32_f16(pa11_, vC3, m11, 0, 0, 0); \
    }                                                                         \
    vC0 = vN0_; vC1 = vN1_; vC2 = vN2_; vC3 = vN3_;                           \
    _Pragma("unroll")                                                         \
    for (int f = 0; f < 4; ++f) kfC[f] = kfN_[f];                             \
  }

__device__ __forceinline__ void phase3(
    int bid, int tid, int w, int lo, int q,
    const short* __restrict__ Qb, const short* __restrict__ Kt,
    const _Float16* __restrict__ Vt2, const float* __restrict__ Zi,
    const float* __restrict__ graph, const float* __restrict__ Wc,
    const float* __restrict__ bc, float* __restrict__ out)
{
  __shared__ __align__(16) unsigned char smem[4 * 2 * 32 * 72 * 2];  // 36864 B
  const int lane = tid & 63;
  const int b = bid & 7;                 // XCD-pinned
  const int n0 = (bid >> 3) << 5;
  _Float16* PA = (_Float16*)smem + (w * 2 + 0) * (32 * 72);
  _Float16* PB = (_Float16*)smem + (w * 2 + 1) * (32 * 72);
  float* MS = (float*)smem;
  const bf16x8 qf0 = *(const bf16x8*)(Qb + ((size_t)b * NN + n0 + lo) * 32 + q * 8);
  const bf16x8 qf1 = *(const bf16x8*)(Qb + ((size_t)b * NN + n0 + 16 + lo) * 32 + q * 8);
  f32x4 m00 = {0,0,0,0}, m01 = {0,0,0,0}, m10 = {0,0,0,0}, m11 = {0,0,0,0};
  const short* ktb = Kt + (size_t)b * LL * 32 + lo * 32 + q * 8;
  const _Float16* vb0 = Vt2 + ((size_t)b * 32 + lo) * LL;
  const _Float16* vb1 = vb0 + (size_t)16 * LL;
  const float* zib = Zi + b * 4096 + q * 4;
  const int lc0 = w * 16;
  bf16x8 kfC[4];
  #pragma unroll
  for (int f = 0; f < 4; ++f)
    kfC[f] = *(const bf16x8*)(ktb + (size_t)(lc0 * 64 + f * 16) * 32);
  f16x8 vC0 = {0,0,0,0,0,0,0,0}, vC1 = {0,0,0,0,0,0,0,0};
  f16x8 vC2 = {0,0,0,0,0,0,0,0}, vC3 = {0,0,0,0,0,0,0,0};
  #pragma unroll 1
  for (int i2 = 0; i2 < 8; ++i2) {
    const int lce = lc0 + i2 * 2;
    KC_BODY(lce, PA, PB, (i2 != 0));
    KC_BODY(lce + 1, PB, PA, true);
  }
  {
    f16x8 pa00_ = *(const f16x8*)&PB[lo * 72 + q * 8];
    f16x8 pa01_ = *(const f16x8*)&PB[lo * 72 + 32 + q * 8];
    f16x8 pa10_ = *(const f16x8*)&PB[(16 + lo) * 72 + q * 8];
    f16x8 pa11_ = *(const f16x8*)&PB[(16 + lo) * 72 + 32 + q * 8];
    m00 = __builtin_amdgcn_mfma_f32_16x16x32_f16(pa00_, vC0, m00, 0, 0, 0);
    m10 = __builtin_amdgcn_mfma_f32_16x16x32_f16(pa10_, vC0, m10, 0, 0, 0);
    m01 = __builtin_amdgcn_mfma_f32_16x16x32_f16(pa00_, vC2, m01, 0, 0, 0);
    m11 = __builtin_amdgcn_mfma_f32_16x16x32_f16(pa10_, vC2, m11, 0, 0, 0);
    m00 = __builtin_amdgcn_mfma_f32_16x16x32_f16(pa01_, vC1, m00, 0, 0, 0);
    m10 = __builtin_amdgcn_mfma_f32_16x16x32_f16(pa11_, vC1, m10, 0, 0, 0);
    m01 = __builtin_amdgcn_mfma_f32_16x16x32_f16(pa01_, vC3, m01, 0, 0, 0);
    m11 = __builtin_amdgcn_mfma_f32_16x16x32_f16(pa11_, vC3, m11, 0, 0, 0);
  }
  float* MSw = MS + w * 2304;
  #pragma unroll
  for (int r = 0; r < 4; ++r) {
    MSw[(q * 4 + r) * 36 + lo] = m00[r];
    MSw[(q * 4 + r) * 36 + 16 + lo] = m01[r];
    MSw[(16 + q * 4 + r) * 36 + lo] = m10[r];
    MSw[(16 + q * 4 + r) * 36 + 16 + lo] = m11[r];
  }
  __syncthreads();
  const int o = lane & 31, nh = lane >> 5;
  float wcr[32];
  #pragma unroll
  for (int c4 = 0; c4 < 8; ++c4) {
    float4 wc4 = *(const float4*)(Wc + o * 32 + c4 * 4);
    wcr[c4 * 4 + 0] = wc4.x * (1.0f / 4096.0f);
    wcr[c4 * 4 + 1] = wc4.y * (1.0f / 4096.0f);
    wcr[c4 * 4 + 2] = wc4.z * (1.0f / 4096.0f);
    wcr[c4 * 4 + 3] = wc4.w * (1.0f / 4096.0f);
  }
  const float bcv = bc[o];
  #pragma unroll
  for (int rr = 0; rr < 4; ++rr) {
    const int nl = w * 8 + nh * 4 + rr;
    f32x4 s = {0,0,0,0};
    #pragma unroll
    for (int cc = 0; cc < 8; ++cc) {
      f32x4 ma = *(const f32x4*)&MS[0 * 2304 + nl * 36 + cc * 4];
      f32x4 mb = *(const f32x4*)&MS[1 * 2304 + nl * 36 + cc * 4];
      f32x4 mc = *(const f32x4*)&MS[2 * 2304 + nl * 36 + cc * 4];
      f32x4 md = *(const f32x4*)&MS[3 * 2304 + nl * 36 + cc * 4];
      f32x4 m4 = ma + mb + mc + md;
      s[0] += wcr[cc * 4 + 0] * m4[0];
      s[1] += wcr[cc * 4 + 1] * m4[1];
      s[2] += wcr[cc * 4 + 2] * m4[2];
      s[3] += wcr[cc * 4 + 3] * m4[3];
    }
    const size_t idx = ((size_t)b * NN + n0 + nl) * 32 + o;
    out[idx] = s[0] + s[1] + s[2] + s[3] + bcv + graph[idx];
  }
}

// ---------------------------------------------------------------------------
// Fused cooperative kernel: 1024 blocks x 256 thr, exactly co-resident
// (LDS 36.9KB -> 4 blocks/CU x 256 CU; launch_bounds(256,4) caps VGPR 128).
// Saves ~3 x 15.5us launch overhead (gap arithmetic fits r1/r2/r3/r6/r9).
// ---------------------------------------------------------------------------
__global__ __launch_bounds__(256, 4) void fused_all(
    const float* __restrict__ graph, const float* __restrict__ img,
    const float* __restrict__ Wq, const float* __restrict__ bq,
    const float* __restrict__ Wk, const float* __restrict__ bk,
    const float* __restrict__ Wv, const float* __restrict__ bv,
    const float* __restrict__ Wc, const float* __restrict__ bc,
    short* __restrict__ Qb, short* __restrict__ Kt, _Float16* __restrict__ Vt2,
    float* __restrict__ Zb, float* __restrict__ Zi, float* __restrict__ out)
{
  cooperative_groups::grid_group grid = cooperative_groups::this_grid();
  const int tid = threadIdx.x;
  const int w = tid >> 6, lane = tid & 63, lo = lane & 15, q = lane >> 4;
  const int bid = blockIdx.x;
  phase0(bid, tid, w, lo, q, graph, img, Wq, bq, Wk, bk, Wv, bv, Qb, Kt, Vt2, Zb);
  grid.sync();
  phase1(bid, w, lo, q, Qb, Kt, Zb);
  grid.sync();
  phase2(bid, tid, Zb, Zi);
  grid.sync();
  phase3(bid, tid, w, lo, q, Qb, Kt, Vt2, Zi, graph, Wc, bc, out);
}

// Fallback standalone kernels (same phase bodies) if cooperative launch fails.
__global__ __launch_bounds__(256, 4) void k_p0(
    const float* __restrict__ graph, const float* __restrict__ img,
    const float* __restrict__ Wq, const float* __restrict__ bq,
    const float* __restrict__ Wk, const float* __restrict__ bk,
    const float* __restrict__ Wv, const float* __restrict__ bv,
    short* __restrict__ Qb, short* __restrict__ Kt, _Float16* __restrict__ Vt2,
    float* __restrict__ Zb)
{
  const int tid = threadIdx.x;
  phase0(blockIdx.x, tid, tid >> 6, tid & 15, (tid & 63) >> 4,
         graph, img, Wq, bq, Wk, bk, Wv, bv, Qb, Kt, Vt2, Zb);
}
__global__ __launch_bounds__(256, 4) void k_p1(
    const short* __restrict__ Qb, const short* __restrict__ Kt,
    float* __restrict__ Zb)
{
  const int tid = threadIdx.x;
  phase1(blockIdx.x, tid >> 6, tid & 15, (tid & 63) >> 4, Qb, Kt, Zb);
}
__global__ __launch_bounds__(256, 4) void k_p2(
    const float* __restrict__ Zb, float* __restrict__ Zi)
{
  phase2(blockIdx.x, threadIdx.x, Zb, Zi);
}
__global__ __launch_bounds__(256, 4) void k_p3(
    const short* __restrict__ Qb, const short* __restrict__ Kt,
    const _Float16* __restrict__ Vt2, const float* __restrict__ Zi,
    const float* __restrict__ graph, const float* __restrict__ Wc,
    const float* __restrict__ bc, float* __restrict__ out)
{
  const int tid = threadIdx.x;
  phase3(blockIdx.x, tid, tid >> 6, tid & 15, (tid & 63) >> 4,
         Qb, Kt, Vt2, Zi, graph, Wc, bc, out);
}

// ---------------------------------------------------------------------------
extern "C" void kernel_launch(void* const* d_in, const int* in_sizes, int n_in,
                              void* d_out, int out_size, void* d_ws, size_t ws_size,
                              hipStream_t stream) {
  const float* graph = (const float*)d_in[0];
  const float* img   = (const float*)d_in[1];
  const float* Wq    = (const float*)d_in[2];
  const float* bq    = (const float*)d_in[3];
  const float* Wk    = (const float*)d_in[4];
  const float* bk    = (const float*)d_in[5];
  const float* Wv    = (const float*)d_in[6];
  const float* bv    = (const float*)d_in[7];
  const float* Wc    = (const float*)d_in[8];
  const float* bc    = (const float*)d_in[9];
  char* ws = (char*)d_ws;
  short*    Qb  = (short*)(ws + 0);          // 2 MB   bf16 [B][N][32]
  short*    Kt  = (short*)(ws + 2097152);    // 2 MB   bf16 [B][L][32] (scaled)
  _Float16* Vt2 = (_Float16*)(ws + 4194304); // 2 MB   f16  [B][32][L] (raw V)
  float*    Zb  = (float*)(ws + 6291456);    // 128 KB f32  [B][L]
  float*    Zi  = (float*)(ws + 6422528);    // 128 KB f32  [B][L] = 4096/Z
  float*    outp = (float*)d_out;
  void* args[] = {
    (void*)&graph, (void*)&img, (void*)&Wq, (void*)&bq, (void*)&Wk, (void*)&bk,
    (void*)&Wv, (void*)&bv, (void*)&Wc, (void*)&bc,
    (void*)&Qb, (void*)&Kt, (void*)&Vt2, (void*)&Zb, (void*)&Zi, (void*)&outp};
  hipError_t err = hipLaunchCooperativeKernel((const void*)fused_all,
                                              dim3(1024), dim3(256), args, 0, stream);
  if (err != hipSuccess) {
    // fallback: 4 plain launches of the same phases
    k_p0<<<dim3(1024), dim3(256), 0, stream>>>(graph, img, Wq, bq, Wk, bk, Wv, bv,
                                               Qb, Kt, Vt2, Zb);
    k_p1<<<dim3(1024), dim3(256), 0, stream>>>(Qb, Kt, Zb);
    k_p2<<<dim3(1024), dim3(256), 0, stream>>>(Zb, Zi);
    k_p3<<<dim3(1024), dim3(256), 0, stream>>>(Qb, Kt, Vt2, Zi, graph, Wc, bc, outp);
  }
}

// Round 11
// 175.922 us; speedup vs baseline: 3.0799x; 3.0799x over previous
//
#include <hip/hip_runtime.h>

#define BB 8
#define NN 4096
#define LL 4096
#define CC 256

typedef short bf16x8 __attribute__((ext_vector_type(8)));
typedef _Float16 f16x8 __attribute__((ext_vector_type(8)));
typedef __fp16 hf16x2 __attribute__((ext_vector_type(2)));  // cvt_pkrtz return type
typedef float f32x4 __attribute__((ext_vector_type(4)));

__device__ __forceinline__ short f2bf(float f) {
  union { float f; unsigned u; } v; v.f = f;
  unsigned r = v.u + 0x7fffu + ((v.u >> 16) & 1u);
  return (short)(r >> 16);
}
// 8 consecutive f32 -> bf16x8 MFMA fragment (two float4 loads)
__device__ __forceinline__ bf16x8 ld8(const float* __restrict__ fp) {
  float4 a = *(const float4*)fp;
  float4 b = *(const float4*)(fp + 4);
  bf16x8 r;
  r[0] = f2bf(a.x); r[1] = f2bf(a.y); r[2] = f2bf(a.z); r[3] = f2bf(a.w);
  r[4] = f2bf(b.x); r[5] = f2bf(b.y); r[6] = f2bf(b.z); r[7] = f2bf(b.w);
  return r;
}

// ---------------------------------------------------------------------------
// Kernel A: projections (unchanged from r7).
// ---------------------------------------------------------------------------
__global__ __launch_bounds__(256) void ka_proj(
    const float* __restrict__ graph, const float* __restrict__ img,
    const float* __restrict__ Wq, const float* __restrict__ bq,
    const float* __restrict__ Wk, const float* __restrict__ bk,
    const float* __restrict__ Wv, const float* __restrict__ bv,
    short* __restrict__ Qb, short* __restrict__ Kt, _Float16* __restrict__ Vt,
    float* __restrict__ Zbuf)
{
  const int tid = threadIdx.x;
  const int w = tid >> 6, lane = tid & 63, lo = lane & 15, q = lane >> 4;
  const int bid = blockIdx.x;
  if (bid < 512) {
    const int b = bid >> 6;
    if (tid < 64) Zbuf[(size_t)b * LL + ((bid & 63) << 6) + tid] = 0.0f;
    const int lt = ((bid & 63) << 6) + (w << 4);
    f32x4 aK0 = {0,0,0,0}, aK1 = {0,0,0,0}, aV0 = {0,0,0,0}, aV1 = {0,0,0,0};
    const float* ib = img + (size_t)b * CC * LL + lt + lo;
    #pragma unroll
    for (int cs = 0; cs < 8; ++cs) {
      const int c0 = cs * 32 + q * 8;
      bf16x8 bi;
      #pragma unroll
      for (int j = 0; j < 8; ++j) bi[j] = f2bf(ib[(size_t)(c0 + j) * LL]);
      bf16x8 wk0 = ld8(Wk + lo * CC + c0);
      bf16x8 wk1 = ld8(Wk + (lo + 16) * CC + c0);
      bf16x8 wv0 = ld8(Wv + lo * CC + c0);
      bf16x8 wv1 = ld8(Wv + (lo + 16) * CC + c0);
      aK0 = __builtin_amdgcn_mfma_f32_16x16x32_bf16(wk0, bi, aK0, 0, 0, 0);
      aK1 = __builtin_amdgcn_mfma_f32_16x16x32_bf16(wk1, bi, aK1, 0, 0, 0);
      aV0 = __builtin_amdgcn_mfma_f32_16x16x32_bf16(wv0, bi, aV0, 0, 0, 0);
      aV1 = __builtin_amdgcn_mfma_f32_16x16x32_bf16(wv1, bi, aV1, 0, 0, 0);
    }
    const float kscale = 0.2550348663f;  // log2(e)/sqrt(32)
    const size_t row = ((size_t)b * LL + lt + lo) * 32;
    short4 s0, s1;
    s0.x = f2bf((aK0[0] + bk[q * 4 + 0]) * kscale);
    s0.y = f2bf((aK0[1] + bk[q * 4 + 1]) * kscale);
    s0.z = f2bf((aK0[2] + bk[q * 4 + 2]) * kscale);
    s0.w = f2bf((aK0[3] + bk[q * 4 + 3]) * kscale);
    s1.x = f2bf((aK1[0] + bk[16 + q * 4 + 0]) * kscale);
    s1.y = f2bf((aK1[1] + bk[16 + q * 4 + 1]) * kscale);
    s1.z = f2bf((aK1[2] + bk[16 + q * 4 + 2]) * kscale);
    s1.w = f2bf((aK1[3] + bk[16 + q * 4 + 3]) * kscale);
    *(short4*)(Kt + row + q * 4) = s0;
    *(short4*)(Kt + row + 16 + q * 4) = s1;
    union { hf16x2 h[2]; uint2 u; } p0, p1;
    p0.h[0] = __builtin_amdgcn_cvt_pkrtz(aV0[0] + bv[q * 4 + 0], aV0[1] + bv[q * 4 + 1]);
    p0.h[1] = __builtin_amdgcn_cvt_pkrtz(aV0[2] + bv[q * 4 + 2], aV0[3] + bv[q * 4 + 3]);
    p1.h[0] = __builtin_amdgcn_cvt_pkrtz(aV1[0] + bv[16 + q * 4 + 0], aV1[1] + bv[16 + q * 4 + 1]);
    p1.h[1] = __builtin_amdgcn_cvt_pkrtz(aV1[2] + bv[16 + q * 4 + 2], aV1[3] + bv[16 + q * 4 + 3]);
    *(uint2*)(Vt + row + q * 4) = p0.u;
    *(uint2*)(Vt + row + 16 + q * 4) = p1.u;
  } else {
    const int t = bid - 512;
    const int b = t >> 6;
    const int nt = ((t & 63) << 6) + (w << 4);
    bf16x8 ag = ld8(graph + ((size_t)b * NN + nt + lo) * 32 + q * 8);
    bf16x8 w0 = ld8(Wq + lo * 32 + q * 8);
    bf16x8 w1 = ld8(Wq + (lo + 16) * 32 + q * 8);
    f32x4 z = {0,0,0,0};
    f32x4 a0 = __builtin_amdgcn_mfma_f32_16x16x32_bf16(ag, w0, z, 0, 0, 0);
    f32x4 a1 = __builtin_amdgcn_mfma_f32_16x16x32_bf16(ag, w1, z, 0, 0, 0);
    const float b0 = bq[lo], b1 = bq[lo + 16];
    #pragma unroll
    for (int r = 0; r < 4; ++r) {
      const size_t rowq = ((size_t)b * NN + nt + q * 4 + r) * 32;
      Qb[rowq + lo] = f2bf(a0[r] + b0);
      Qb[rowq + 16 + lo] = f2bf(a1[r] + b1);
    }
  }
}

// ---------------------------------------------------------------------------
// Kernel B1: partial softmax denominators, 128-l tiles (was 64): halves the
// Q re-read traffic (each Q row now read 32x not 64x -> 0.25 MB/CU).
// 1024 blocks (b=bid&7 XCD-pinned, 32 l-tiles, 4 n-quarters) x 4 waves.
// ---------------------------------------------------------------------------
__global__ __launch_bounds__(256) void kb1_z(
    const short* __restrict__ Qb, const short* __restrict__ Kt,
    float* __restrict__ Z)
{
  const int tid = threadIdx.x;
  const int w = tid >> 6, lane = tid & 63, lo = lane & 15, q = lane >> 4;
  const int bid = blockIdx.x;
  const int b = bid & 7;           // XCD-partition: one b per XCD
  const int t = bid >> 3;          // 0..127 within the XCD
  const int l0 = (t >> 2) << 7;    // 32 tiles of 128 l
  const int nq = t & 3;
  bf16x8 kf[8];
  #pragma unroll
  for (int f = 0; f < 8; ++f)
    kf[f] = *(const bf16x8*)(Kt + ((size_t)b * LL + l0 + f * 16 + lo) * 32 + q * 8);
  float za[8][4] = {{0}};
  const short* qbase = Qb + ((size_t)b * NN + nq * 1024 + w * 256 + lo) * 32 + q * 8;
  #pragma unroll 4
  for (int it = 0; it < 16; ++it) {
    bf16x8 qf = *(const bf16x8*)(qbase + it * 512);
    #pragma unroll
    for (int f = 0; f < 8; ++f) {
      f32x4 z = {0,0,0,0};
      f32x4 c = __builtin_amdgcn_mfma_f32_16x16x32_bf16(kf[f], qf, z, 0, 0, 0);
      #pragma unroll
      for (int r = 0; r < 4; ++r) za[f][r] += __builtin_amdgcn_exp2f(c[r]);
    }
  }
  #pragma unroll
  for (int m = 1; m < 16; m <<= 1)
    #pragma unroll
    for (int f = 0; f < 8; ++f)
      #pragma unroll
      for (int r = 0; r < 4; ++r)
        za[f][r] += __shfl_xor(za[f][r], m, 64);
  if (lo == 0) {
    #pragma unroll
    for (int f = 0; f < 8; ++f)
      #pragma unroll
      for (int r = 0; r < 4; ++r)
        atomicAdd(&Z[(size_t)b * LL + l0 + f * 16 + q * 4 + r], za[f][r]);
  }
}

// ---------------------------------------------------------------------------
// Kernel B2: Vpp[b][o][l] = Vt[b][l][o] * (4096 / Z_l)  (unchanged).
// ---------------------------------------------------------------------------
__global__ __launch_bounds__(256) void kb2_scale(
    const _Float16* __restrict__ Vt, const float* __restrict__ Z,
    _Float16* __restrict__ Vpp)
{
  const int tid = threadIdx.x;
  const int b = blockIdx.x >> 6;
  const int l = ((blockIdx.x & 63) << 6) + (tid & 63);
  const int og = tid >> 6;  // 0..3
  const float inv = __builtin_amdgcn_rcpf(Z[(size_t)b * LL + l]) * 4096.0f;
  const f16x8 vv = *(const f16x8*)(Vt + ((size_t)b * LL + l) * 32 + og * 8);
  #pragma unroll
  for (int j = 0; j < 8; ++j)
    Vpp[((size_t)b * 32 + og * 8 + j) * LL + l] = (_Float16)((float)vv[j] * inv);
}

// ---------------------------------------------------------------------------
// Kernel C v3: 64-n tiles.  r1-r10 established kc's 57.5us floor tracks
// per-CU cache-line traffic (~2.5 MB/CU at ~0.25 lines/cy = 56us); traffic
// = n-tile-count x K/V size, so only BIGGER n-tiles reduce it.  512 blocks
// (b=bid&7 XCD-pinned, 64 n-tiles of 64 rows) x 4 independent waves (wave =
// 1024 l, serial r1-style body -- pipelining measured neutral r1==r4).
// 2 blocks/CU -> ~1.1 MB/CU, half of r7.  No lockstep barriers (r9 lesson).
// Per-wave P region [64 n][72] f16 = 9216 B; msg partials overlay it after
// the loop; cross-wave sum in epilogue (waves split l).  Numerics == r7.
// ---------------------------------------------------------------------------
__global__ __launch_bounds__(256) void kc_attn(
    const short* __restrict__ Qb, const short* __restrict__ Kt,
    const _Float16* __restrict__ Vpp, const float* __restrict__ graph,
    const float* __restrict__ Wc, const float* __restrict__ bc,
    float* __restrict__ out)
{
  __shared__ __align__(16) unsigned char smem[4 * 9216];  // 36864 B
  const int tid = threadIdx.x;
  const int w = tid >> 6, lane = tid & 63, lo = lane & 15, q = lane >> 4;
  const int b = blockIdx.x & 7;               // XCD-pinned: one b per XCD
  const int n0 = ((int)blockIdx.x >> 3) << 6; // 64 n-tiles of 64 rows
  _Float16* Pw = (_Float16*)(smem + w * 9216);  // [64 n][72]
  bf16x8 qf[4];
  #pragma unroll
  for (int nq = 0; nq < 4; ++nq)
    qf[nq] = *(const bf16x8*)(Qb + ((size_t)b * NN + n0 + nq * 16 + lo) * 32 + q * 8);
  f32x4 m[4][2];
  #pragma unroll
  for (int nq = 0; nq < 4; ++nq) {
    m[nq][0] = (f32x4){0,0,0,0};
    m[nq][1] = (f32x4){0,0,0,0};
  }
  const short* ktb = Kt + (size_t)b * LL * 32 + lo * 32 + q * 8;
  const _Float16* vb0 = Vpp + ((size_t)b * 32 + lo) * LL;
  const _Float16* vb1 = vb0 + (size_t)16 * LL;
  const int lc0 = w * 16;
  for (int lc = lc0; lc < lc0 + 16; ++lc) {
    const int lbase = lc * 64;
    bf16x8 kf[4];
    #pragma unroll
    for (int f = 0; f < 4; ++f)
      kf[f] = *(const bf16x8*)(ktb + (size_t)(lbase + f * 16) * 32);
    f16x8 vA0 = *(const f16x8*)(vb0 + lbase + q * 8);
    f16x8 vA1 = *(const f16x8*)(vb0 + lbase + 32 + q * 8);
    f16x8 vB0 = *(const f16x8*)(vb1 + lbase + q * 8);
    f16x8 vB1 = *(const f16x8*)(vb1 + lbase + 32 + q * 8);
    #pragma unroll
    for (int nq = 0; nq < 4; ++nq)
      #pragma unroll
      for (int f = 0; f < 4; ++f) {
        f32x4 z = {0,0,0,0};
        f32x4 c = __builtin_amdgcn_mfma_f32_16x16x32_bf16(kf[f], qf[nq], z, 0, 0, 0);
        union { hf16x2 h[2]; uint2 u; } pk;
        pk.h[0] = __builtin_amdgcn_cvt_pkrtz(__builtin_amdgcn_exp2f(c[0]),
                                             __builtin_amdgcn_exp2f(c[1]));
        pk.h[1] = __builtin_amdgcn_cvt_pkrtz(__builtin_amdgcn_exp2f(c[2]),
                                             __builtin_amdgcn_exp2f(c[3]));
        *(uint2*)&Pw[(nq * 16 + lo) * 72 + f * 16 + q * 4] = pk.u;
      }
    #pragma unroll
    for (int nq = 0; nq < 4; ++nq) {
      f16x8 pa0 = *(const f16x8*)&Pw[(nq * 16 + lo) * 72 + q * 8];
      f16x8 pa1 = *(const f16x8*)&Pw[(nq * 16 + lo) * 72 + 32 + q * 8];
      m[nq][0] = __builtin_amdgcn_mfma_f32_16x16x32_f16(pa0, vA0, m[nq][0], 0, 0, 0);
      m[nq][1] = __builtin_amdgcn_mfma_f32_16x16x32_f16(pa0, vB0, m[nq][1], 0, 0, 0);
      m[nq][0] = __builtin_amdgcn_mfma_f32_16x16x32_f16(pa1, vA1, m[nq][0], 0, 0, 0);
      m[nq][1] = __builtin_amdgcn_mfma_f32_16x16x32_f16(pa1, vB1, m[nq][1], 0, 0, 0);
    }
  }
  // stash msg partials into this wave's OWN P region ([64 n][36] f32 = 9216 B)
  float* MSw = (float*)(smem + w * 9216);
  #pragma unroll
  for (int nq = 0; nq < 4; ++nq)
    #pragma unroll
    for (int r = 0; r < 4; ++r) {
      MSw[(nq * 16 + q * 4 + r) * 36 + lo] = m[nq][0][r];
      MSw[(nq * 16 + q * 4 + r) * 36 + 16 + lo] = m[nq][1][r];
    }
  __syncthreads();
  // epilogue: out[n][o] = graph + bc[o] + sum_c Wc[o][c]*msg[n][c] / 4096
  const float* MS = (const float*)smem;  // 4 regions, stride 2304 f32
  const int o = lane & 31, nh = lane >> 5;
  float wcr[32];
  #pragma unroll
  for (int c4 = 0; c4 < 8; ++c4) {
    float4 wc4 = *(const float4*)(Wc + o * 32 + c4 * 4);
    wcr[c4 * 4 + 0] = wc4.x * (1.0f / 4096.0f);
    wcr[c4 * 4 + 1] = wc4.y * (1.0f / 4096.0f);
    wcr[c4 * 4 + 2] = wc4.z * (1.0f / 4096.0f);
    wcr[c4 * 4 + 3] = wc4.w * (1.0f / 4096.0f);
  }
  const float bcv = bc[o];
  #pragma unroll
  for (int rr = 0; rr < 8; ++rr) {
    const int nl = w * 16 + nh * 8 + rr;  // 0..63
    f32x4 s = {0,0,0,0};
    #pragma unroll
    for (int cc = 0; cc < 8; ++cc) {
      f32x4 ma = *(const f32x4*)&MS[0 * 2304 + nl * 36 + cc * 4];
      f32x4 mb = *(const f32x4*)&MS[1 * 2304 + nl * 36 + cc * 4];
      f32x4 mc = *(const f32x4*)&MS[2 * 2304 + nl * 36 + cc * 4];
      f32x4 md = *(const f32x4*)&MS[3 * 2304 + nl * 36 + cc * 4];
      f32x4 m4 = ma + mb + mc + md;
      s[0] += wcr[cc * 4 + 0] * m4[0];
      s[1] += wcr[cc * 4 + 1] * m4[1];
      s[2] += wcr[cc * 4 + 2] * m4[2];
      s[3] += wcr[cc * 4 + 3] * m4[3];
    }
    const size_t idx = ((size_t)b * NN + n0 + nl) * 32 + o;
    out[idx] = s[0] + s[1] + s[2] + s[3] + bcv + graph[idx];
  }
}

// ---------------------------------------------------------------------------
extern "C" void kernel_launch(void* const* d_in, const int* in_sizes, int n_in,
                              void* d_out, int out_size, void* d_ws, size_t ws_size,
                              hipStream_t stream) {
  const float* graph = (const float*)d_in[0];
  const float* img   = (const float*)d_in[1];
  const float* Wq    = (const float*)d_in[2];
  const float* bq    = (const float*)d_in[3];
  const float* Wk    = (const float*)d_in[4];
  const float* bk    = (const float*)d_in[5];
  const float* Wv    = (const float*)d_in[6];
  const float* bv    = (const float*)d_in[7];
  const float* Wc    = (const float*)d_in[8];
  const float* bc    = (const float*)d_in[9];
  char* ws = (char*)d_ws;
  short*    Qb  = (short*)(ws + 0);          // 2 MB   bf16 [B][N][32]
  short*    Kt  = (short*)(ws + 2097152);    // 2 MB   bf16 [B][L][32] (scaled)
  _Float16* Vt  = (_Float16*)(ws + 4194304); // 2 MB   f16  [B][L][32]
  _Float16* Vpp = (_Float16*)(ws + 6291456); // 2 MB   f16  [B][32][L] (V*4096/Z)
  float*    Zb  = (float*)(ws + 8388608);    // 128 KB f32  [B][L]
  ka_proj<<<dim3(1024), dim3(256), 0, stream>>>(graph, img, Wq, bq, Wk, bk, Wv, bv,
                                                Qb, Kt, Vt, Zb);
  kb1_z<<<dim3(1024), dim3(256), 0, stream>>>(Qb, Kt, Zb);
  kb2_scale<<<dim3(512), dim3(256), 0, stream>>>(Vt, Zb, Vpp);
  kc_attn<<<dim3(512), dim3(256), 0, stream>>>(Qb, Kt, Vpp, graph, Wc, bc,
                                               (float*)d_out);
}

// Round 12
// 175.704 us; speedup vs baseline: 3.0837x; 1.0012x over previous
//
#include <hip/hip_runtime.h>

#define BB 8
#define NN 4096
#define LL 4096
#define CC 256

typedef short bf16x8 __attribute__((ext_vector_type(8)));
typedef _Float16 f16x8 __attribute__((ext_vector_type(8)));
typedef __fp16 hf16x2 __attribute__((ext_vector_type(2)));  // cvt_pkrtz return type
typedef float f32x4 __attribute__((ext_vector_type(4)));

__device__ __forceinline__ short f2bf(float f) {
  union { float f; unsigned u; } v; v.f = f;
  unsigned r = v.u + 0x7fffu + ((v.u >> 16) & 1u);
  return (short)(r >> 16);
}
// 8 consecutive f32 -> bf16x8 MFMA fragment (two float4 loads)
__device__ __forceinline__ bf16x8 ld8(const float* __restrict__ fp) {
  float4 a = *(const float4*)fp;
  float4 b = *(const float4*)(fp + 4);
  bf16x8 r;
  r[0] = f2bf(a.x); r[1] = f2bf(a.y); r[2] = f2bf(a.z); r[3] = f2bf(a.w);
  r[4] = f2bf(b.x); r[5] = f2bf(b.y); r[6] = f2bf(b.z); r[7] = f2bf(b.w);
  return r;
}

// ---------------------------------------------------------------------------
// Kernel A: projections (unchanged).
// ---------------------------------------------------------------------------
__global__ __launch_bounds__(256) void ka_proj(
    const float* __restrict__ graph, const float* __restrict__ img,
    const float* __restrict__ Wq, const float* __restrict__ bq,
    const float* __restrict__ Wk, const float* __restrict__ bk,
    const float* __restrict__ Wv, const float* __restrict__ bv,
    short* __restrict__ Qb, short* __restrict__ Kt, _Float16* __restrict__ Vt,
    float* __restrict__ Zbuf)
{
  const int tid = threadIdx.x;
  const int w = tid >> 6, lane = tid & 63, lo = lane & 15, q = lane >> 4;
  const int bid = blockIdx.x;
  if (bid < 512) {
    const int b = bid >> 6;
    if (tid < 64) Zbuf[(size_t)b * LL + ((bid & 63) << 6) + tid] = 0.0f;
    const int lt = ((bid & 63) << 6) + (w << 4);
    f32x4 aK0 = {0,0,0,0}, aK1 = {0,0,0,0}, aV0 = {0,0,0,0}, aV1 = {0,0,0,0};
    const float* ib = img + (size_t)b * CC * LL + lt + lo;
    #pragma unroll
    for (int cs = 0; cs < 8; ++cs) {
      const int c0 = cs * 32 + q * 8;
      bf16x8 bi;
      #pragma unroll
      for (int j = 0; j < 8; ++j) bi[j] = f2bf(ib[(size_t)(c0 + j) * LL]);
      bf16x8 wk0 = ld8(Wk + lo * CC + c0);
      bf16x8 wk1 = ld8(Wk + (lo + 16) * CC + c0);
      bf16x8 wv0 = ld8(Wv + lo * CC + c0);
      bf16x8 wv1 = ld8(Wv + (lo + 16) * CC + c0);
      aK0 = __builtin_amdgcn_mfma_f32_16x16x32_bf16(wk0, bi, aK0, 0, 0, 0);
      aK1 = __builtin_amdgcn_mfma_f32_16x16x32_bf16(wk1, bi, aK1, 0, 0, 0);
      aV0 = __builtin_amdgcn_mfma_f32_16x16x32_bf16(wv0, bi, aV0, 0, 0, 0);
      aV1 = __builtin_amdgcn_mfma_f32_16x16x32_bf16(wv1, bi, aV1, 0, 0, 0);
    }
    const float kscale = 0.2550348663f;  // log2(e)/sqrt(32)
    const size_t row = ((size_t)b * LL + lt + lo) * 32;
    short4 s0, s1;
    s0.x = f2bf((aK0[0] + bk[q * 4 + 0]) * kscale);
    s0.y = f2bf((aK0[1] + bk[q * 4 + 1]) * kscale);
    s0.z = f2bf((aK0[2] + bk[q * 4 + 2]) * kscale);
    s0.w = f2bf((aK0[3] + bk[q * 4 + 3]) * kscale);
    s1.x = f2bf((aK1[0] + bk[16 + q * 4 + 0]) * kscale);
    s1.y = f2bf((aK1[1] + bk[16 + q * 4 + 1]) * kscale);
    s1.z = f2bf((aK1[2] + bk[16 + q * 4 + 2]) * kscale);
    s1.w = f2bf((aK1[3] + bk[16 + q * 4 + 3]) * kscale);
    *(short4*)(Kt + row + q * 4) = s0;
    *(short4*)(Kt + row + 16 + q * 4) = s1;
    union { hf16x2 h[2]; uint2 u; } p0, p1;
    p0.h[0] = __builtin_amdgcn_cvt_pkrtz(aV0[0] + bv[q * 4 + 0], aV0[1] + bv[q * 4 + 1]);
    p0.h[1] = __builtin_amdgcn_cvt_pkrtz(aV0[2] + bv[q * 4 + 2], aV0[3] + bv[q * 4 + 3]);
    p1.h[0] = __builtin_amdgcn_cvt_pkrtz(aV1[0] + bv[16 + q * 4 + 0], aV1[1] + bv[16 + q * 4 + 1]);
    p1.h[1] = __builtin_amdgcn_cvt_pkrtz(aV1[2] + bv[16 + q * 4 + 2], aV1[3] + bv[16 + q * 4 + 3]);
    *(uint2*)(Vt + row + q * 4) = p0.u;
    *(uint2*)(Vt + row + 16 + q * 4) = p1.u;
  } else {
    const int t = bid - 512;
    const int b = t >> 6;
    const int nt = ((t & 63) << 6) + (w << 4);
    bf16x8 ag = ld8(graph + ((size_t)b * NN + nt + lo) * 32 + q * 8);
    bf16x8 w0 = ld8(Wq + lo * 32 + q * 8);
    bf16x8 w1 = ld8(Wq + (lo + 16) * 32 + q * 8);
    f32x4 z = {0,0,0,0};
    f32x4 a0 = __builtin_amdgcn_mfma_f32_16x16x32_bf16(ag, w0, z, 0, 0, 0);
    f32x4 a1 = __builtin_amdgcn_mfma_f32_16x16x32_bf16(ag, w1, z, 0, 0, 0);
    const float b0 = bq[lo], b1 = bq[lo + 16];
    #pragma unroll
    for (int r = 0; r < 4; ++r) {
      const size_t rowq = ((size_t)b * NN + nt + q * 4 + r) * 32;
      Qb[rowq + lo] = f2bf(a0[r] + b0);
      Qb[rowq + 16 + lo] = f2bf(a1[r] + b1);
    }
  }
}

// ---------------------------------------------------------------------------
// Kernel B1: partial softmax denominators, 128-l tiles (unchanged from r11).
// ---------------------------------------------------------------------------
__global__ __launch_bounds__(256) void kb1_z(
    const short* __restrict__ Qb, const short* __restrict__ Kt,
    float* __restrict__ Z)
{
  const int tid = threadIdx.x;
  const int w = tid >> 6, lane = tid & 63, lo = lane & 15, q = lane >> 4;
  const int bid = blockIdx.x;
  const int b = bid & 7;           // XCD-partition: one b per XCD
  const int t = bid >> 3;          // 0..127 within the XCD
  const int l0 = (t >> 2) << 7;    // 32 tiles of 128 l
  const int nq = t & 3;
  bf16x8 kf[8];
  #pragma unroll
  for (int f = 0; f < 8; ++f)
    kf[f] = *(const bf16x8*)(Kt + ((size_t)b * LL + l0 + f * 16 + lo) * 32 + q * 8);
  float za[8][4] = {{0}};
  const short* qbase = Qb + ((size_t)b * NN + nq * 1024 + w * 256 + lo) * 32 + q * 8;
  #pragma unroll 4
  for (int it = 0; it < 16; ++it) {
    bf16x8 qf = *(const bf16x8*)(qbase + it * 512);
    #pragma unroll
    for (int f = 0; f < 8; ++f) {
      f32x4 z = {0,0,0,0};
      f32x4 c = __builtin_amdgcn_mfma_f32_16x16x32_bf16(kf[f], qf, z, 0, 0, 0);
      #pragma unroll
      for (int r = 0; r < 4; ++r) za[f][r] += __builtin_amdgcn_exp2f(c[r]);
    }
  }
  #pragma unroll
  for (int m = 1; m < 16; m <<= 1)
    #pragma unroll
    for (int f = 0; f < 8; ++f)
      #pragma unroll
      for (int r = 0; r < 4; ++r)
        za[f][r] += __shfl_xor(za[f][r], m, 64);
  if (lo == 0) {
    #pragma unroll
    for (int f = 0; f < 8; ++f)
      #pragma unroll
      for (int r = 0; r < 4; ++r)
        atomicAdd(&Z[(size_t)b * LL + l0 + f * 16 + q * 4 + r], za[f][r]);
  }
}

// ---------------------------------------------------------------------------
// Kernel B2: Vpp[b][o][l] = Vt[b][l][o] * (4096 / Z_l)  (unchanged).
// ---------------------------------------------------------------------------
__global__ __launch_bounds__(256) void kb2_scale(
    const _Float16* __restrict__ Vt, const float* __restrict__ Z,
    _Float16* __restrict__ Vpp)
{
  const int tid = threadIdx.x;
  const int b = blockIdx.x >> 6;
  const int l = ((blockIdx.x & 63) << 6) + (tid & 63);
  const int og = tid >> 6;  // 0..3
  const float inv = __builtin_amdgcn_rcpf(Z[(size_t)b * LL + l]) * 4096.0f;
  const f16x8 vv = *(const f16x8*)(Vt + ((size_t)b * LL + l) * 32 + og * 8);
  #pragma unroll
  for (int j = 0; j < 8; ++j)
    Vpp[((size_t)b * 32 + og * 8 + j) * LL + l] = (_Float16)((float)vv[j] * inv);
}

// ---------------------------------------------------------------------------
// Kernel C v4: 128-n tiles.  r11 confirmed the per-CU K/V line-traffic model
// (64-n: 2.5->1.1 MB/CU, kc 57.5 -> <41us).  Next step: 256 blocks (1/CU,
// b=bid&7 XCD-pinned) x 512 thr (8 waves = 2/SIMD); block = 128 n; wave =
// 512 l (8 lc).  Per-CU traffic 512 KB (~13us floor).  P reused across 4
// sub-phases of 2 nq ([32][72] f16/wave x 8 waves = 36.9 KB); per-wave
// buffers, no lockstep staging (r9 lesson).  Epilogue: 4 passes of 32 n
// (stash -> barrier -> 8-wave reduce -> barrier).  Numerics == r11.
// ---------------------------------------------------------------------------
__global__ __launch_bounds__(512) void kc_attn(
    const short* __restrict__ Qb, const short* __restrict__ Kt,
    const _Float16* __restrict__ Vpp, const float* __restrict__ graph,
    const float* __restrict__ Wc, const float* __restrict__ bc,
    float* __restrict__ out)
{
  __shared__ __align__(16) unsigned char smem[8 * 4608];  // 36864 B
  const int tid = threadIdx.x;
  const int w = tid >> 6, lane = tid & 63, lo = lane & 15, q = lane >> 4;
  const int b = blockIdx.x & 7;               // XCD-pinned: one b per XCD
  const int n0 = ((int)blockIdx.x >> 3) << 7; // 32 n-tiles of 128 rows
  _Float16* Pw = (_Float16*)(smem + w * 4608);  // [32 n][72] per wave
  bf16x8 qf[8];
  #pragma unroll
  for (int nq = 0; nq < 8; ++nq)
    qf[nq] = *(const bf16x8*)(Qb + ((size_t)b * NN + n0 + nq * 16 + lo) * 32 + q * 8);
  f32x4 m[8][2];
  #pragma unroll
  for (int nq = 0; nq < 8; ++nq) {
    m[nq][0] = (f32x4){0,0,0,0};
    m[nq][1] = (f32x4){0,0,0,0};
  }
  const short* ktb = Kt + (size_t)b * LL * 32 + lo * 32 + q * 8;
  const _Float16* vb0 = Vpp + ((size_t)b * 32 + lo) * LL;
  const _Float16* vb1 = vb0 + (size_t)16 * LL;
  const int lc0 = w * 8;
  for (int lc = lc0; lc < lc0 + 8; ++lc) {
    const int lbase = lc * 64;
    bf16x8 kf[4];
    #pragma unroll
    for (int f = 0; f < 4; ++f)
      kf[f] = *(const bf16x8*)(ktb + (size_t)(lbase + f * 16) * 32);
    f16x8 vA0 = *(const f16x8*)(vb0 + lbase + q * 8);
    f16x8 vA1 = *(const f16x8*)(vb0 + lbase + 32 + q * 8);
    f16x8 vB0 = *(const f16x8*)(vb1 + lbase + q * 8);
    f16x8 vB1 = *(const f16x8*)(vb1 + lbase + 32 + q * 8);
    #pragma unroll
    for (int p = 0; p < 4; ++p) {
      #pragma unroll
      for (int h = 0; h < 2; ++h) {
        const int nq = p * 2 + h;
        #pragma unroll
        for (int f = 0; f < 4; ++f) {
          f32x4 z = {0,0,0,0};
          f32x4 c = __builtin_amdgcn_mfma_f32_16x16x32_bf16(kf[f], qf[nq], z, 0, 0, 0);
          union { hf16x2 hh[2]; uint2 u; } pk;
          pk.hh[0] = __builtin_amdgcn_cvt_pkrtz(__builtin_amdgcn_exp2f(c[0]),
                                                __builtin_amdgcn_exp2f(c[1]));
          pk.hh[1] = __builtin_amdgcn_cvt_pkrtz(__builtin_amdgcn_exp2f(c[2]),
                                                __builtin_amdgcn_exp2f(c[3]));
          *(uint2*)&Pw[(h * 16 + lo) * 72 + f * 16 + q * 4] = pk.u;
        }
      }
      #pragma unroll
      for (int h = 0; h < 2; ++h) {
        const int nq = p * 2 + h;
        f16x8 pa0 = *(const f16x8*)&Pw[(h * 16 + lo) * 72 + q * 8];
        f16x8 pa1 = *(const f16x8*)&Pw[(h * 16 + lo) * 72 + 32 + q * 8];
        m[nq][0] = __builtin_amdgcn_mfma_f32_16x16x32_f16(pa0, vA0, m[nq][0], 0, 0, 0);
        m[nq][1] = __builtin_amdgcn_mfma_f32_16x16x32_f16(pa0, vB0, m[nq][1], 0, 0, 0);
        m[nq][0] = __builtin_amdgcn_mfma_f32_16x16x32_f16(pa1, vA1, m[nq][0], 0, 0, 0);
        m[nq][1] = __builtin_amdgcn_mfma_f32_16x16x32_f16(pa1, vB1, m[nq][1], 0, 0, 0);
      }
    }
  }
  // epilogue: 4 passes of 32 n; out[n][o] = graph + bc[o] + Wc@msg/4096
  const int o = lane & 31, nh = lane >> 5;
  float wcr[32];
  #pragma unroll
  for (int c4 = 0; c4 < 8; ++c4) {
    float4 wc4 = *(const float4*)(Wc + o * 32 + c4 * 4);
    wcr[c4 * 4 + 0] = wc4.x * (1.0f / 4096.0f);
    wcr[c4 * 4 + 1] = wc4.y * (1.0f / 4096.0f);
    wcr[c4 * 4 + 2] = wc4.z * (1.0f / 4096.0f);
    wcr[c4 * 4 + 3] = wc4.w * (1.0f / 4096.0f);
  }
  const float bcv = bc[o];
  float* MSw = (float*)(smem + w * 4608);       // [32 n][36] f32, own region
  const float* MS = (const float*)smem;         // 8 regions, stride 1152 f32
  #pragma unroll
  for (int p = 0; p < 4; ++p) {
    __syncthreads();  // prior pass's cross-wave reads (or loop P reads) done
    #pragma unroll
    for (int h = 0; h < 2; ++h) {
      const int nq = p * 2 + h;
      #pragma unroll
      for (int r = 0; r < 4; ++r) {
        MSw[(h * 16 + q * 4 + r) * 36 + lo] = m[nq][0][r];
        MSw[(h * 16 + q * 4 + r) * 36 + 16 + lo] = m[nq][1][r];
      }
    }
    __syncthreads();
    #pragma unroll
    for (int rr = 0; rr < 2; ++rr) {
      const int nr = w * 4 + nh * 2 + rr;  // 0..31
      f32x4 s = {0,0,0,0};
      #pragma unroll
      for (int cc = 0; cc < 8; ++cc) {
        f32x4 a4 = *(const f32x4*)&MS[0 * 1152 + nr * 36 + cc * 4];
        #pragma unroll
        for (int k = 1; k < 8; ++k)
          a4 += *(const f32x4*)&MS[k * 1152 + nr * 36 + cc * 4];
        s[0] += wcr[cc * 4 + 0] * a4[0];
        s[1] += wcr[cc * 4 + 1] * a4[1];
        s[2] += wcr[cc * 4 + 2] * a4[2];
        s[3] += wcr[cc * 4 + 3] * a4[3];
      }
      const size_t idx = ((size_t)b * NN + n0 + p * 32 + nr) * 32 + o;
      out[idx] = s[0] + s[1] + s[2] + s[3] + bcv + graph[idx];
    }
  }
}

// ---------------------------------------------------------------------------
extern "C" void kernel_launch(void* const* d_in, const int* in_sizes, int n_in,
                              void* d_out, int out_size, void* d_ws, size_t ws_size,
                              hipStream_t stream) {
  const float* graph = (const float*)d_in[0];
  const float* img   = (const float*)d_in[1];
  const float* Wq    = (const float*)d_in[2];
  const float* bq    = (const float*)d_in[3];
  const float* Wk    = (const float*)d_in[4];
  const float* bk    = (const float*)d_in[5];
  const float* Wv    = (const float*)d_in[6];
  const float* bv    = (const float*)d_in[7];
  const float* Wc    = (const float*)d_in[8];
  const float* bc    = (const float*)d_in[9];
  char* ws = (char*)d_ws;
  short*    Qb  = (short*)(ws + 0);          // 2 MB   bf16 [B][N][32]
  short*    Kt  = (short*)(ws + 2097152);    // 2 MB   bf16 [B][L][32] (scaled)
  _Float16* Vt  = (_Float16*)(ws + 4194304); // 2 MB   f16  [B][L][32]
  _Float16* Vpp = (_Float16*)(ws + 6291456); // 2 MB   f16  [B][32][L] (V*4096/Z)
  float*    Zb  = (float*)(ws + 8388608);    // 128 KB f32  [B][L]
  ka_proj<<<dim3(1024), dim3(256), 0, stream>>>(graph, img, Wq, bq, Wk, bk, Wv, bv,
                                                Qb, Kt, Vt, Zb);
  kb1_z<<<dim3(1024), dim3(256), 0, stream>>>(Qb, Kt, Zb);
  kb2_scale<<<dim3(512), dim3(256), 0, stream>>>(Vt, Zb, Vpp);
  kc_attn<<<dim3(256), dim3(512), 0, stream>>>(Qb, Kt, Vpp, graph, Wc, bc,
                                               (float*)d_out);
}